// Round 3
// baseline (454.489 us; speedup 1.0000x reference)
//
#include <hip/hip_runtime.h>
#include <hip/hip_bf16.h>

typedef unsigned long long u64;

#define H_SZ 4096
#define NBITS 16
#define NFEAT 128
#define NCLS 10
#define THETA 8

// Bit convention everywhere: for chunk c of 256 positions, word (c,j) j=0..3,
// bit i <-> position p = c*256 + 4*i + j  (what per-component ballots of a
// lane-major float4 produce). Mask words: index c*8 + j*2 + t (t=0 pos,1 neg).

// ---------------------------------------------------------------------------
// Encode: x[64,128] -> thermometer bits, actp0[(c*4+j)*64 + b], c=0..7.
// ---------------------------------------------------------------------------
__global__ void encode_kernel(const float* __restrict__ x, u64* __restrict__ actp0) {
    int idx = blockIdx.x * blockDim.x + threadIdx.x;   // 0..2047
    if (idx >= 32 * 64) return;
    int wword = idx >> 6;        // 0..31
    int b = idx & 63;
    int c = wword >> 2, j = wword & 3;
    u64 word = 0;
    for (int i = 0; i < 64; i++) {
        int p = c * 256 + 4 * i + j;
        int f = p >> 4, t = p & 15;
        float thr = (t + 1.0f) / (NBITS + 1.0f);   // identical fp32 math to ref
        if (x[b * NFEAT + f] >= thr) word |= (1ULL << i);
    }
    actp0[wword * 64 + b] = word;
}

// ---------------------------------------------------------------------------
// Convert: pure streaming W (fp32) -> sign bitmasks. Wave handles 4 contiguous
// chunks (4 KB); per chunk: float4/lane load, 8 ballots, lanes 0..7 store the
// 8 mask words. No dependencies -> saturates HBM.
// grid: nchunks/16 blocks x 256 thr (4 waves x 4 chunks).
// ---------------------------------------------------------------------------
__global__ __launch_bounds__(256) void convert_kernel(const float* __restrict__ W,
                                                      u64* __restrict__ masks) {
    int lane = threadIdx.x & 63;
    int wave = blockIdx.x * 4 + (threadIdx.x >> 6);
    #pragma unroll
    for (int k = 0; k < 4; k++) {
        int c = wave * 4 + k;
        float4 v = ((const float4*)W)[(size_t)c * 64 + lane];
        u64 m0 = __ballot(v.x > 0.0f);
        u64 m1 = __ballot(v.x < 0.0f);
        u64 m2 = __ballot(v.y > 0.0f);
        u64 m3 = __ballot(v.y < 0.0f);
        u64 m4 = __ballot(v.z > 0.0f);
        u64 m5 = __ballot(v.z < 0.0f);
        u64 m6 = __ballot(v.w > 0.0f);
        u64 m7 = __ballot(v.w < 0.0f);
        u64 w = m0;
        w = (lane == 1) ? m1 : w;
        w = (lane == 2) ? m2 : w;
        w = (lane == 3) ? m3 : w;
        w = (lane == 4) ? m4 : w;
        w = (lane == 5) ? m5 : w;
        w = (lane == 6) ? m6 : w;
        w = (lane == 7) ? m7 : w;
        if (lane < 8) masks[(size_t)c * 8 + lane] = w;
    }
}

// ---------------------------------------------------------------------------
// Layer from masks: wave = one (h,s) row. Mask row (NC*8 u64, 0.5-1 KB) via
// wave-uniform broadcast loads (L1/L2-hot); acts from LDS (lane = batch);
// popcount-accumulate; fired ballot out. grid: 2048 blocks x 256 thr.
// ---------------------------------------------------------------------------
template <int NC>   // chunks per row: 8 (P=2048) / 16 (P=4096)
__global__ __launch_bounds__(256) void layer_mask_kernel(const u64* __restrict__ masks,
                                                         const u64* __restrict__ actp,
                                                         u64* __restrict__ ballots) {
    __shared__ u64 lds[NC * 4 * 64];      // 16 KB / 32 KB
    int tid = threadIdx.x;
    for (int i = tid; i < NC * 4 * 64; i += 256) lds[i] = actp[i];
    __syncthreads();

    int lane = tid & 63;
    int wid = blockIdx.x * 4 + (tid >> 6);             // row 0..8191
    const u64* mrow = masks + (size_t)wid * (NC * 8);
    int z = 0;
    #pragma unroll
    for (int c = 0; c < NC; c++) {
        #pragma unroll
        for (int j = 0; j < 4; j++) {
            u64 p = mrow[c * 8 + j * 2];
            u64 n = mrow[c * 8 + j * 2 + 1];
            u64 a = lds[(c * 4 + j) * 64 + lane];
            z += __builtin_popcountll(a & p) - __builtin_popcountll(a & n);
        }
    }
    u64 fz = __ballot(z >= THETA);
    if (lane == 0) ballots[wid] = fz;
}

// ---------------------------------------------------------------------------
// Transpose: ballots[h*2+s] (bit b = batch) -> f[h] = OR segs + next-layer act
// words in the interleaved convention. grid: 16 blocks x 256 thr.
// ---------------------------------------------------------------------------
__global__ void transpose_kernel(const u64* __restrict__ ballots,
                                 u64* __restrict__ f,
                                 u64* __restrict__ actp) {
    __shared__ u64 lds[256];
    int c = blockIdx.x;
    int tid = threadIdx.x;
    int h = c * 256 + tid;
    u64 fh = ballots[2 * h] | ballots[2 * h + 1];
    f[h] = fh;
    lds[tid] = fh;
    __syncthreads();
    int j = tid >> 6, b = tid & 63;
    u64 word = 0;
    #pragma unroll 8
    for (int i = 0; i < 64; i++)
        word |= ((lds[4 * i + j] >> b) & 1ULL) << i;
    actp[(c * 4 + j) * 64 + b] = word;
}

// ---------------------------------------------------------------------------
// Output: out[b,c] = sum_l sum_h fired_l[b,h] * outW[l,h,c]. lane = batch.
// grid: 480 blocks x 256 thr.
// ---------------------------------------------------------------------------
__global__ void output_kernel(const float* __restrict__ outW,
                              const u64* __restrict__ f,
                              float* __restrict__ out) {
    int tid = threadIdx.x;
    int lane = tid & 63;
    int wid = blockIdx.x * 4 + (tid >> 6);   // 0..1919
    int l = wid / (NCLS * 64);
    int rem = wid % (NCLS * 64);
    int c = rem / 64;
    int chunk = rem % 64;
    const u64* fl = f + l * H_SZ;
    int h0 = chunk * 64;
    float acc = 0.0f;
    #pragma unroll 8
    for (int h = h0; h < h0 + 64; h++) {
        float wv = outW[((size_t)(l * H_SZ + h)) * NCLS + c];
        u64 ball = fl[h];
        if ((ball >> lane) & 1ULL) acc += wv;
    }
    atomicAdd(&out[lane * NCLS + c], acc);
}

// ---------------------------------------------------------------------------
extern "C" void kernel_launch(void* const* d_in, const int* in_sizes, int n_in,
                              void* d_out, int out_size, void* d_ws, size_t ws_size,
                              hipStream_t stream) {
    const float* x    = (const float*)d_in[0];
    const float* W0   = (const float*)d_in[1];
    const float* W1   = (const float*)d_in[2];
    const float* W2   = (const float*)d_in[3];
    const float* outW = (const float*)d_in[4];
    float* out = (float*)d_out;

    // workspace layout (u64-aligned)
    char* ws = (char*)d_ws;
    u64* actp0   = (u64*)(ws);                    // 2048 u64  = 16 KB
    u64* actp1   = (u64*)(ws + 16384);            // 4096 u64  = 32 KB
    u64* actp2   = (u64*)(ws + 49152);            // 4096 u64  = 32 KB
    u64* ballots = (u64*)(ws + 81920);            // 8192 u64  = 64 KB
    u64* f       = (u64*)(ws + 147456);           // 3*4096 u64 = 96 KB
    u64* scratch = (u64*)(ws + 245760);
    u64* mask0   = (u64*)(ws + (1u << 20));       // 8192 rows x  64 words = 4 MB
    u64* mask1   = (u64*)(ws + (6u << 20));       // 8192 rows x 128 words = 8 MB
    u64* mask2   = (u64*)(ws + (15u << 20));      // 8192 rows x 128 words = 8 MB

    hipMemsetAsync(d_out, 0, (size_t)out_size * sizeof(float), stream);

    encode_kernel<<<8, 256, 0, stream>>>(x, actp0);

    // pure streaming sign-extraction: 320 MB -> 20 MB bitmasks, HBM-bound
    convert_kernel<<<4096, 256, 0, stream>>>(W0, mask0);   // 65536 chunks
    convert_kernel<<<8192, 256, 0, stream>>>(W1, mask1);   // 131072 chunks
    convert_kernel<<<8192, 256, 0, stream>>>(W2, mask2);   // 131072 chunks

    layer_mask_kernel<8><<<2048, 256, 0, stream>>>(mask0, actp0, ballots);
    transpose_kernel<<<16, 256, 0, stream>>>(ballots, f + 0 * H_SZ, actp1);

    layer_mask_kernel<16><<<2048, 256, 0, stream>>>(mask1, actp1, ballots);
    transpose_kernel<<<16, 256, 0, stream>>>(ballots, f + 1 * H_SZ, actp2);

    layer_mask_kernel<16><<<2048, 256, 0, stream>>>(mask2, actp2, ballots);
    transpose_kernel<<<16, 256, 0, stream>>>(ballots, f + 2 * H_SZ, scratch);

    output_kernel<<<480, 256, 0, stream>>>(outW, f, out);
}

// Round 4
// 401.747 us; speedup vs baseline: 1.1313x; 1.1313x over previous
//
#include <hip/hip_runtime.h>
#include <hip/hip_bf16.h>

typedef unsigned long long u64;

#define H_SZ 4096
#define NBITS 16
#define NFEAT 128
#define NCLS 10
#define THETA 8

// Bit convention: for chunk c of 256 positions, word (c,j) j=0..3 has bit
// i <-> position p = c*256 + 4*i + j (what per-component ballots of a
// lane-major float4 load produce). Acts packed the same way -> AND+popcount
// is exact regardless of bit order.

// ---------------------------------------------------------------------------
// Encode: x[64,128] -> thermometer bits, actp0[(c*4+j)*64 + b], c=0..7.
// ---------------------------------------------------------------------------
__global__ void encode_kernel(const float* __restrict__ x, u64* __restrict__ actp0) {
    int idx = blockIdx.x * blockDim.x + threadIdx.x;   // 0..2047
    if (idx >= 32 * 64) return;
    int wword = idx >> 6;        // 0..31
    int b = idx & 63;
    int c = wword >> 2, j = wword & 3;
    u64 word = 0;
    for (int i = 0; i < 64; i++) {
        int p = c * 256 + 4 * i + j;
        int f = p >> 4, t = p & 15;
        float thr = (t + 1.0f) / (NBITS + 1.0f);   // identical fp32 math to ref
        if (x[b * NFEAT + f] >= thr) word |= (1ULL << i);
    }
    actp0[wword * 64 + b] = word;
}

// ---------------------------------------------------------------------------
// Layer (fused, register-pipelined): wave = ONE (h,s) row. The full row is
// loaded into a register array first (8/16 independent global_load_dwordx4 in
// flight -> latency-hidden stream), then ballots -> wave-uniform sign masks,
// AND with per-batch act words (lane = batch) from LDS, popcount-accumulate.
// __launch_bounds__(256,2): VGPR budget <=256 (v[16] = 64 payload VGPRs, no
// spill), >=2 blocks/CU -> 32 MB in flight chip-wide >> HBM BDP.
// grid: 2048 blocks x 256 thr = 8192 waves = H*S rows.
// ---------------------------------------------------------------------------
template <int P>
__global__ __launch_bounds__(256, 2) void layer_kernel(const float* __restrict__ W,
                                                       const u64* __restrict__ actp,
                                                       u64* __restrict__ ballots) {
    constexpr int NW = P / 64;      // act words
    constexpr int NCH = P / 256;    // float4 chunks per row per lane
    __shared__ u64 lds[NW * 64];    // 16 KB (P=2048) / 32 KB (P=4096)
    int tid = threadIdx.x;
    for (int i = tid; i < NW * 64; i += 256) lds[i] = actp[i];
    __syncthreads();

    int lane = tid & 63;
    int wid = blockIdx.x * 4 + (tid >> 6);   // (h,s) row 0..8191
    const float4* wrow = (const float4*)(W + (size_t)wid * P) + lane;

    // Stage 1: issue the whole row's loads back-to-back (independent).
    float4 v[NCH];
    #pragma unroll
    for (int c = 0; c < NCH; c++) v[c] = wrow[c * 64];

    // Stage 2: ballots + popcounts (overlaps the tail of the load stream).
    unsigned int zp = 0, zn = 0;
    #pragma unroll
    for (int c = 0; c < NCH; c++) {
        u64 p0 = __ballot(v[c].x > 0.0f);
        u64 n0 = __ballot(v[c].x < 0.0f);
        u64 p1 = __ballot(v[c].y > 0.0f);
        u64 n1 = __ballot(v[c].y < 0.0f);
        u64 p2 = __ballot(v[c].z > 0.0f);
        u64 n2 = __ballot(v[c].z < 0.0f);
        u64 p3 = __ballot(v[c].w > 0.0f);
        u64 n3 = __ballot(v[c].w < 0.0f);
        u64 a0 = lds[(c * 4 + 0) * 64 + lane];
        u64 a1 = lds[(c * 4 + 1) * 64 + lane];
        u64 a2 = lds[(c * 4 + 2) * 64 + lane];
        u64 a3 = lds[(c * 4 + 3) * 64 + lane];
        zp += __builtin_popcountll(a0 & p0) + __builtin_popcountll(a1 & p1)
            + __builtin_popcountll(a2 & p2) + __builtin_popcountll(a3 & p3);
        zn += __builtin_popcountll(a0 & n0) + __builtin_popcountll(a1 & n1)
            + __builtin_popcountll(a2 & n2) + __builtin_popcountll(a3 & n3);
    }
    int z = (int)zp - (int)zn;
    u64 fz = __ballot(z >= THETA);
    if (lane == 0) ballots[wid] = fz;
}

// ---------------------------------------------------------------------------
// Transpose: ballots[h*2+s] (bit b = batch) -> f[h] = OR segs (batch-major)
// + next-layer act words in the interleaved convention. grid: 16 x 256.
// ---------------------------------------------------------------------------
__global__ void transpose_kernel(const u64* __restrict__ ballots,
                                 u64* __restrict__ f,
                                 u64* __restrict__ actp) {
    __shared__ u64 lds[256];
    int c = blockIdx.x;
    int tid = threadIdx.x;
    int h = c * 256 + tid;
    u64 fh = ballots[2 * h] | ballots[2 * h + 1];
    f[h] = fh;
    lds[tid] = fh;
    __syncthreads();
    int j = tid >> 6, b = tid & 63;
    u64 word = 0;
    #pragma unroll 8
    for (int i = 0; i < 64; i++)
        word |= ((lds[4 * i + j] >> b) & 1ULL) << i;
    actp[(c * 4 + j) * 64 + b] = word;
}

// ---------------------------------------------------------------------------
// Output: out[b,c] = sum_l sum_h fired_l[b,h] * outW[l,h,c]. lane = batch.
// grid: 480 blocks x 256 thr = 1920 waves (3 layers x 10 classes x 64 chunks).
// ---------------------------------------------------------------------------
__global__ void output_kernel(const float* __restrict__ outW,
                              const u64* __restrict__ f,
                              float* __restrict__ out) {
    int tid = threadIdx.x;
    int lane = tid & 63;
    int wid = blockIdx.x * 4 + (tid >> 6);   // 0..1919
    int l = wid / (NCLS * 64);
    int rem = wid % (NCLS * 64);
    int c = rem / 64;
    int chunk = rem % 64;
    const u64* fl = f + l * H_SZ;
    int h0 = chunk * 64;
    float acc = 0.0f;
    #pragma unroll 8
    for (int h = h0; h < h0 + 64; h++) {
        float wv = outW[((size_t)(l * H_SZ + h)) * NCLS + c];
        u64 ball = fl[h];
        if ((ball >> lane) & 1ULL) acc += wv;
    }
    atomicAdd(&out[lane * NCLS + c], acc);
}

// ---------------------------------------------------------------------------
extern "C" void kernel_launch(void* const* d_in, const int* in_sizes, int n_in,
                              void* d_out, int out_size, void* d_ws, size_t ws_size,
                              hipStream_t stream) {
    const float* x    = (const float*)d_in[0];
    const float* W0   = (const float*)d_in[1];
    const float* W1   = (const float*)d_in[2];
    const float* W2   = (const float*)d_in[3];
    const float* outW = (const float*)d_in[4];
    float* out = (float*)d_out;

    // workspace layout (u64-aligned)
    char* ws = (char*)d_ws;
    u64* actp0   = (u64*)(ws);                    // 2048 u64  = 16 KB
    u64* actp1   = (u64*)(ws + 16384);            // 4096 u64  = 32 KB
    u64* actp2   = (u64*)(ws + 49152);            // 4096 u64  = 32 KB
    u64* ballots = (u64*)(ws + 81920);            // 8192 u64  = 64 KB
    u64* f       = (u64*)(ws + 147456);           // 3*4096 u64 = 96 KB
    u64* scratch = (u64*)(ws + 245760);           // dummy actp for last transpose

    hipMemsetAsync(d_out, 0, (size_t)out_size * sizeof(float), stream);

    encode_kernel<<<8, 256, 0, stream>>>(x, actp0);

    layer_kernel<2048><<<2048, 256, 0, stream>>>(W0, actp0, ballots);
    transpose_kernel<<<16, 256, 0, stream>>>(ballots, f + 0 * H_SZ, actp1);

    layer_kernel<4096><<<2048, 256, 0, stream>>>(W1, actp1, ballots);
    transpose_kernel<<<16, 256, 0, stream>>>(ballots, f + 1 * H_SZ, actp2);

    layer_kernel<4096><<<2048, 256, 0, stream>>>(W2, actp2, ballots);
    transpose_kernel<<<16, 256, 0, stream>>>(ballots, f + 2 * H_SZ, scratch);

    output_kernel<<<480, 256, 0, stream>>>(outW, f, out);
}

// Round 5
// 395.600 us; speedup vs baseline: 1.1489x; 1.0155x over previous
//
#include <hip/hip_runtime.h>
#include <hip/hip_bf16.h>

typedef unsigned long long u64;

#define H_SZ 4096
#define NBITS 16
#define NFEAT 128
#define NCLS 10
#define THETA 8

// Bit convention: for chunk c of 256 positions, word (c,j) j=0..3 has bit
// i <-> position p = c*256 + 4*i + j (what per-component ballots of a
// lane-major float4 load produce). Acts packed identically -> AND+popcount
// is exact regardless of bit order.

// ---------------------------------------------------------------------------
// Encode: x[64,128] -> thermometer bits, actp0[(c*4+j)*64 + b], c=0..7.
// ---------------------------------------------------------------------------
__global__ void encode_kernel(const float* __restrict__ x, u64* __restrict__ actp0) {
    int idx = blockIdx.x * blockDim.x + threadIdx.x;   // 0..2047
    if (idx >= 32 * 64) return;
    int wword = idx >> 6;        // 0..31
    int b = idx & 63;
    int c = wword >> 2, j = wword & 3;
    u64 word = 0;
    for (int i = 0; i < 64; i++) {
        int p = c * 256 + 4 * i + j;
        int f = p >> 4, t = p & 15;
        float thr = (t + 1.0f) / (NBITS + 1.0f);   // identical fp32 math to ref
        if (x[b * NFEAT + f] >= thr) word |= (1ULL << i);
    }
    actp0[wword * 64 + b] = word;
}

// ---------------------------------------------------------------------------
// Layer (software-pipelined stream): wave = ROWS consecutive (h,s) rows =
// one contiguous 16/32 KB weight stream. A/B register double-buffer of 8 KB
// groups: loads for group g+1 are in flight while group g is balloted and
// popcounted against per-batch act words (lane = batch) from LDS. Every wave
// keeps ~8 KB outstanding for its whole lifetime (continuous-issue, the m13
// copy-kernel property). __launch_bounds__(256,4): <=128 VGPRs -> 4 blocks/CU
// co-resident -> 16 waves/CU x 8 KB ~ 128 KB/CU in flight; grid is exactly
// one generation (no relaunch gaps).
// ---------------------------------------------------------------------------
template <int NCH, int ROWS>   // NCH = 256-pos chunks per row (8 or 16)
__global__ __launch_bounds__(256, 4) void layer_kernel(const float* __restrict__ W,
                                                       const u64* __restrict__ actp,
                                                       u64* __restrict__ ballots) {
    constexpr int NW = NCH * 4;          // act words
    constexpr int G = 8;                 // chunks per group (8 KB/wave)
    constexpr int TG = ROWS * NCH / G;   // groups per wave
    __shared__ u64 lds[NW * 64];         // 16 KB / 32 KB
    int tid = threadIdx.x;
    for (int i = tid; i < NW * 64; i += 256) lds[i] = actp[i];
    __syncthreads();

    int lane = tid & 63;
    int wave = blockIdx.x * 4 + (tid >> 6);
    int wid0 = wave * ROWS;              // first (h,s) row of this wave
    const float4* base = (const float4*)(W + (size_t)wid0 * (NCH * 256)) + lane;

    float4 A[G], B[G];
    #pragma unroll
    for (int k = 0; k < G; k++) A[k] = base[k * 64];

    int z = 0;
    #pragma unroll
    for (int g = 0; g < TG; g++) {
        float4* cur = (g & 1) ? B : A;
        float4* nxt = (g & 1) ? A : B;
        if (g + 1 < TG) {
            #pragma unroll
            for (int k = 0; k < G; k++) nxt[k] = base[((g + 1) * G + k) * 64];
        }
        #pragma unroll
        for (int k = 0; k < G; k++) {
            int c = (g * G + k) % NCH;   // chunk within row (compile-time)
            float4 v = cur[k];
            u64 p0 = __ballot(v.x > 0.0f);
            u64 n0 = __ballot(v.x < 0.0f);
            u64 p1 = __ballot(v.y > 0.0f);
            u64 n1 = __ballot(v.y < 0.0f);
            u64 p2 = __ballot(v.z > 0.0f);
            u64 n2 = __ballot(v.z < 0.0f);
            u64 p3 = __ballot(v.w > 0.0f);
            u64 n3 = __ballot(v.w < 0.0f);
            u64 a0 = lds[(c * 4 + 0) * 64 + lane];
            u64 a1 = lds[(c * 4 + 1) * 64 + lane];
            u64 a2 = lds[(c * 4 + 2) * 64 + lane];
            u64 a3 = lds[(c * 4 + 3) * 64 + lane];
            z += __builtin_popcountll(a0 & p0) - __builtin_popcountll(a0 & n0)
               + __builtin_popcountll(a1 & p1) - __builtin_popcountll(a1 & n1)
               + __builtin_popcountll(a2 & p2) - __builtin_popcountll(a2 & n2)
               + __builtin_popcountll(a3 & p3) - __builtin_popcountll(a3 & n3);
        }
        if (((g + 1) * G) % NCH == 0) {  // row boundary: emit fired ballot
            u64 fz = __ballot(z >= THETA);
            int r = ((g + 1) * G) / NCH - 1;
            if (lane == 0) ballots[wid0 + r] = fz;
            z = 0;
        }
    }
}

// ---------------------------------------------------------------------------
// Transpose: ballots[h*2+s] (bit b = batch) -> f[h] = OR segs (batch-major)
// + next-layer act words in the interleaved convention. grid: 16 x 256.
// ---------------------------------------------------------------------------
__global__ void transpose_kernel(const u64* __restrict__ ballots,
                                 u64* __restrict__ f,
                                 u64* __restrict__ actp) {
    __shared__ u64 lds[256];
    int c = blockIdx.x;
    int tid = threadIdx.x;
    int h = c * 256 + tid;
    u64 fh = ballots[2 * h] | ballots[2 * h + 1];
    f[h] = fh;
    lds[tid] = fh;
    __syncthreads();
    int j = tid >> 6, b = tid & 63;
    u64 word = 0;
    #pragma unroll 8
    for (int i = 0; i < 64; i++)
        word |= ((lds[4 * i + j] >> b) & 1ULL) << i;
    actp[(c * 4 + j) * 64 + b] = word;
}

// ---------------------------------------------------------------------------
// Output: out[b,c] = sum_l sum_h fired_l[b,h] * outW[l,h,c]. lane = batch.
// grid: 480 blocks x 256 thr = 1920 waves (3 layers x 10 classes x 64 chunks).
// ---------------------------------------------------------------------------
__global__ void output_kernel(const float* __restrict__ outW,
                              const u64* __restrict__ f,
                              float* __restrict__ out) {
    int tid = threadIdx.x;
    int lane = tid & 63;
    int wid = blockIdx.x * 4 + (tid >> 6);   // 0..1919
    int l = wid / (NCLS * 64);
    int rem = wid % (NCLS * 64);
    int c = rem / 64;
    int chunk = rem % 64;
    const u64* fl = f + l * H_SZ;
    int h0 = chunk * 64;
    float acc = 0.0f;
    #pragma unroll 8
    for (int h = h0; h < h0 + 64; h++) {
        float wv = outW[((size_t)(l * H_SZ + h)) * NCLS + c];
        u64 ball = fl[h];
        if ((ball >> lane) & 1ULL) acc += wv;
    }
    atomicAdd(&out[lane * NCLS + c], acc);
}

// ---------------------------------------------------------------------------
extern "C" void kernel_launch(void* const* d_in, const int* in_sizes, int n_in,
                              void* d_out, int out_size, void* d_ws, size_t ws_size,
                              hipStream_t stream) {
    const float* x    = (const float*)d_in[0];
    const float* W0   = (const float*)d_in[1];
    const float* W1   = (const float*)d_in[2];
    const float* W2   = (const float*)d_in[3];
    const float* outW = (const float*)d_in[4];
    float* out = (float*)d_out;

    // workspace layout (u64-aligned)
    char* ws = (char*)d_ws;
    u64* actp0   = (u64*)(ws);                    // 2048 u64  = 16 KB
    u64* actp1   = (u64*)(ws + 16384);            // 4096 u64  = 32 KB
    u64* actp2   = (u64*)(ws + 49152);            // 4096 u64  = 32 KB
    u64* ballots = (u64*)(ws + 81920);            // 8192 u64  = 64 KB
    u64* f       = (u64*)(ws + 147456);           // 3*4096 u64 = 96 KB
    u64* scratch = (u64*)(ws + 245760);           // dummy actp for last transpose

    hipMemsetAsync(d_out, 0, (size_t)out_size * sizeof(float), stream);

    encode_kernel<<<8, 256, 0, stream>>>(x, actp0);

    // 8192 rows, 2 rows/wave -> 4096 waves -> 1024 blocks (one generation)
    layer_kernel<8, 2><<<1024, 256, 0, stream>>>(W0, actp0, ballots);
    transpose_kernel<<<16, 256, 0, stream>>>(ballots, f + 0 * H_SZ, actp1);

    layer_kernel<16, 2><<<1024, 256, 0, stream>>>(W1, actp1, ballots);
    transpose_kernel<<<16, 256, 0, stream>>>(ballots, f + 1 * H_SZ, actp2);

    layer_kernel<16, 2><<<1024, 256, 0, stream>>>(W2, actp2, ballots);
    transpose_kernel<<<16, 256, 0, stream>>>(ballots, f + 2 * H_SZ, scratch);

    output_kernel<<<480, 256, 0, stream>>>(outW, f, out);
}